// Round 4
// baseline (429.020 us; speedup 1.0000x reference)
//
#include <hip/hip_runtime.h>
#include <cstdint>
#include <cstddef>

// Problem constants
#define M_DIM 8192
#define N_DIM 4096
#define K_DIM 4096

#define BM 128
#define BN 128
#define BK 64   // int8 elements per K-step (64 bytes per LDS row)

using i32x4  = __attribute__((ext_vector_type(4)))  int;
using i32x16 = __attribute__((ext_vector_type(16))) int;

__device__ __forceinline__ void async_load16(const void* g, void* l) {
    __builtin_amdgcn_global_load_lds(
        (const __attribute__((address_space(1))) void*)g,
        (__attribute__((address_space(3))) void*)l,
        16, 0, 0);
}

// Pack int32 values (range [-128,127]) to int8 for BOTH x and w in one
// dispatch (one int4 in -> one packed uint32 out per thread; both packs
// were already BW-bound, fusing just removes a launch gap).
__global__ __launch_bounds__(256) void pack_i8_fused_kernel(const int4* __restrict__ xsrc,
                                                            const int4* __restrict__ wsrc,
                                                            unsigned* __restrict__ xdst,
                                                            unsigned* __restrict__ wdst,
                                                            long nx4, long ntot4) {
    long i = (long)blockIdx.x * blockDim.x + threadIdx.x;
    if (i >= ntot4) return;
    const int4* src;
    unsigned* dst;
    long si;
    if (i < nx4) { src = xsrc; dst = xdst; si = i; }
    else         { src = wsrc; dst = wdst; si = i - nx4; }
    int4 a = src[si];
    dst[si] = (unsigned)((a.x & 0xff) | ((a.y & 0xff) << 8) |
                         ((a.z & 0xff) << 16) | (a.w << 24));
}

// C[m][n] = sum_k A[m][k]*B[n][k]  (both K-contiguous, int8), then
// out = clamp(round((acc + bias[n]) * (0.05*wscale[n]/0.1)), -128, 127) as int32.
//
// LDS bank-conflict fix: staging writes are forced linear by global_load_lds
// (wave-uniform base + lane*16), so instead of padding we XOR-swizzle which
// GLOBAL 16B chunk lands in each LDS slot: slot (row, c_phys) holds global
// chunk c_phys ^ ((row>>1)&3). Fragment reads un-swizzle. A 16-lane b128
// phase (consecutive rows, fixed logical chunk) then covers all 8 bank-quads
// 2-way (free) instead of 8-way.
__global__ __launch_bounds__(256) void qgemm_i8_kernel(const int8_t* __restrict__ A,
                                                       const int8_t* __restrict__ B,
                                                       const int* __restrict__ bias,
                                                       const float* __restrict__ wscale,
                                                       int* __restrict__ C) {
    __shared__ int8_t As[BM * BK];   // 8 KiB, 128 rows x 64B (chunk-swizzled)
    __shared__ int8_t Bs[BN * BK];   // 8 KiB

    const int tid  = threadIdx.x;
    const int wave = tid >> 6;
    const int lane = tid & 63;
    const int bm = blockIdx.y;
    const int bn = blockIdx.x;

    const int8_t* Ab = A + (size_t)bm * BM * K_DIM;
    const int8_t* Bb = B + (size_t)bn * BN * K_DIM;

    const int wm = wave >> 1;   // 0..1 : row half of 128x128 tile
    const int wn = wave & 1;    // 0..1 : col half

    i32x16 acc[2][2] = {};      // 2x2 grid of 32x32 tiles per wave

    // staging geometry: each wave-issue covers 16 rows x 64B = 1 KiB linear LDS.
    // source chunk is swizzled: c_log = (lane&3) ^ ((row>>1)&3); row%16 = lane>>2,
    // and segment bases are multiples of 16 rows so (row>>1)&3 == ((lane>>2)>>1)&3.
    const int srow = lane >> 2;                               // 0..15
    const int scol = (((lane & 3) ^ ((srow >> 1) & 3))) * 16; // swizzled source chunk

    // fragment geometry (mfma_i32_32x32x32_i8):
    //   A[m][k]: m = lane&31, k = (lane>>5)*16 + j  (16 bytes/lane)
    //   within BK=64: kstep s in {0,1}; logical chunk = s*2 + (lane>>5)
    const int l31 = lane & 31;
    const int khalf = lane >> 5;    // 0..1

    for (int kt = 0; kt < K_DIM; kt += BK) {
#pragma unroll
        for (int c = 0; c < 2; ++c) {
            const int rbase = (c * 4 + wave) * 16;
            async_load16(Ab + (size_t)(rbase + srow) * K_DIM + kt + scol,
                         &As[(c * 4 + wave) * 1024]);
            async_load16(Bb + (size_t)(rbase + srow) * K_DIM + kt + scol,
                         &Bs[(c * 4 + wave) * 1024]);
        }
        __syncthreads();

        i32x4 af[2][2], bf[2][2];   // [tile][kstep]
#pragma unroll
        for (int t = 0; t < 2; ++t) {
            const int am = wm * 64 + t * 32 + l31;
            const int bn_r = wn * 64 + t * 32 + l31;
            const int aswz = (am >> 1) & 3;
            const int bswz = (bn_r >> 1) & 3;
#pragma unroll
            for (int s = 0; s < 2; ++s) {
                const int clog = s * 2 + khalf;
                af[t][s] = *(const i32x4*)&As[am   * BK + ((clog ^ aswz) * 16)];
                bf[t][s] = *(const i32x4*)&Bs[bn_r * BK + ((clog ^ bswz) * 16)];
            }
        }

#pragma unroll
        for (int s = 0; s < 2; ++s)
#pragma unroll
            for (int ti = 0; ti < 2; ++ti)
#pragma unroll
                for (int tj = 0; tj < 2; ++tj)
                    acc[ti][tj] = __builtin_amdgcn_mfma_i32_32x32x32_i8(
                        af[ti][s], bf[tj][s], acc[ti][tj], 0, 0, 0);

        __syncthreads();
    }

    // Epilogue. 32x32 C/D layout: col = lane&31, row = (reg&3) + 8*(reg>>2) + 4*(lane>>5)
#pragma unroll
    for (int tj = 0; tj < 2; ++tj) {
        const int col = bn * BN + wn * 64 + tj * 32 + l31;
        float s = 0.05f * wscale[col];
        s = s / 0.1f;                      // match np ref arithmetic exactly
        const float bz = (float)bias[col];
#pragma unroll
        for (int ti = 0; ti < 2; ++ti) {
            const int row0 = bm * BM + wm * 64 + ti * 32 + 4 * khalf;
#pragma unroll
            for (int reg = 0; reg < 16; ++reg) {
                const int row = row0 + (reg & 3) + 8 * (reg >> 2);
                float v = ((float)acc[ti][tj][reg] + bz) * s;
                v = rintf(v);              // RTNE, matches np.round
                v = fminf(fmaxf(v, -128.0f), 127.0f);
                C[(size_t)row * N_DIM + col] = (int)v;
            }
        }
    }
}

extern "C" void kernel_launch(void* const* d_in, const int* in_sizes, int n_in,
                              void* d_out, int out_size, void* d_ws, size_t ws_size,
                              hipStream_t stream) {
    const int*   x32    = (const int*)d_in[0];     // int8 values promoted to int32
    const int*   w32    = (const int*)d_in[1];
    const int*   bias   = (const int*)d_in[2];
    const float* wscale = (const float*)d_in[3];
    int*         out    = (int*)d_out;

    int8_t* xp = (int8_t*)d_ws;                         // 32 MiB packed x
    int8_t* wp = xp + (size_t)M_DIM * K_DIM;            // 16 MiB packed w

    {
        long nx4   = (long)M_DIM * K_DIM / 4;
        long nw4   = (long)N_DIM * K_DIM / 4;
        long ntot4 = nx4 + nw4;
        pack_i8_fused_kernel<<<(int)((ntot4 + 255) / 256), 256, 0, stream>>>(
            (const int4*)x32, (const int4*)w32,
            (unsigned*)xp, (unsigned*)wp, nx4, ntot4);
    }

    dim3 grid(N_DIM / BN, M_DIM / BM);   // (32, 64)
    qgemm_i8_kernel<<<grid, 256, 0, stream>>>(xp, wp, bias, wscale, out);
}

// Round 5
// 422.222 us; speedup vs baseline: 1.0161x; 1.0161x over previous
//
#include <hip/hip_runtime.h>
#include <cstdint>
#include <cstddef>

// Problem constants
#define M_DIM 8192
#define N_DIM 4096
#define K_DIM 4096

#define BM 128
#define BN 128
#define BK 128  // int8 K-elements per barrier; stored as 2 panels of 64B rows

using i32x4 = __attribute__((ext_vector_type(4))) int;

__device__ __forceinline__ void async_load16(const void* g, void* l) {
    __builtin_amdgcn_global_load_lds(
        (const __attribute__((address_space(1))) void*)g,
        (__attribute__((address_space(3))) void*)l,
        16, 0, 0);
}

// Pack int32 values (range [-128,127]) to int8 for BOTH x and w in one
// dispatch (one int4 in -> one packed uint32 out per thread).
__global__ __launch_bounds__(256) void pack_i8_fused_kernel(const int4* __restrict__ xsrc,
                                                            const int4* __restrict__ wsrc,
                                                            unsigned* __restrict__ xdst,
                                                            unsigned* __restrict__ wdst,
                                                            long nx4, long ntot4) {
    long i = (long)blockIdx.x * blockDim.x + threadIdx.x;
    if (i >= ntot4) return;
    const int4* src;
    unsigned* dst;
    long si;
    if (i < nx4) { src = xsrc; dst = xdst; si = i; }
    else         { src = wsrc; dst = wdst; si = i - nx4; }
    int4 a = src[si];
    dst[si] = (unsigned)((a.x & 0xff) | ((a.y & 0xff) << 8) |
                         ((a.z & 0xff) << 16) | (a.w << 24));
}

// C[m][n] = sum_k A[m][k]*B[n][k]  (both K-contiguous, int8), then
// out = clamp(round((acc + bias[n]) * (0.05*wscale[n]/0.1)), -128, 127) as int32.
//
// BK=128 via two half-K panels: LDS tile As[2][128][64]. global_load_lds's
// LDS side is linear (base + lane*16) but the GLOBAL side is per-lane, so
// each issue gathers (row = rb*16 + lane>>2, khalf p, chunk = lane&3) from
// global into panel p. Read-side geometry (64-B rows) is identical to the
// verified BK=64 kernel; barriers halve, 32 MFMA per barrier.
// NOTE: SQ_LDS_BANK_CONFLICT ~1.68e7 here is 8 cyc/global_load_lds_dwordx4
// (1 KiB = 8 LDS rows written) — inherent write occupancy, not fixable
// read conflicts (proven: invariant across read-pattern rewrites R3/R4).
__global__ __launch_bounds__(256) void qgemm_i8_kernel(const int8_t* __restrict__ A,
                                                       const int8_t* __restrict__ B,
                                                       const int* __restrict__ bias,
                                                       const float* __restrict__ wscale,
                                                       int* __restrict__ C) {
    __shared__ int8_t As[2 * BM * 64];   // 16 KiB: [panel][row][64B]
    __shared__ int8_t Bs[2 * BN * 64];   // 16 KiB

    const int tid  = threadIdx.x;
    const int wave = tid >> 6;
    const int lane = tid & 63;
    const int bm = blockIdx.y;
    const int bn = blockIdx.x;

    const int8_t* Ab = A + (size_t)bm * BM * K_DIM;
    const int8_t* Bb = B + (size_t)bn * BN * K_DIM;

    const int wm = wave >> 1;   // 0..1 : row half of tile
    const int wn = wave & 1;    // 0..1 : col half

    i32x4 acc[4][4] = {};       // 4x4 grid of 16x16 tiles per wave (16 indep accs)

    // staging geometry: lane -> (row-in-16, chunk)
    const int rowoff = lane >> 2;        // 0..15
    const int coff   = (lane & 3) * 16;  // 0/16/32/48

    // fragment geometry (mfma_i32_16x16x64_i8): m = lane&15, 16B/lane of K
    const int kq   = (lane >> 4) * 16;   // byte offset within 64B panel row
    const int mrow = wm * 64 + (lane & 15);
    const int nrow = wn * 64 + (lane & 15);

    for (int kt = 0; kt < K_DIM; kt += BK) {
#pragma unroll
        for (int c = 0; c < 4; ++c) {
            const int g  = c * 4 + wave;   // 0..15
            const int p  = g >> 3;         // panel (k-half)
            const int rb = g & 7;          // 16-row block
            const size_t goff = (size_t)(rb * 16 + rowoff) * K_DIM + kt + p * 64 + coff;
            async_load16(Ab + goff, &As[g * 1024]);
            async_load16(Bb + goff, &Bs[g * 1024]);
        }
        __syncthreads();

#pragma unroll
        for (int p = 0; p < 2; ++p) {
            i32x4 af[4], bf[4];
#pragma unroll
            for (int i = 0; i < 4; ++i)
                af[i] = *(const i32x4*)&As[p * 8192 + (mrow + i * 16) * 64 + kq];
#pragma unroll
            for (int j = 0; j < 4; ++j)
                bf[j] = *(const i32x4*)&Bs[p * 8192 + (nrow + j * 16) * 64 + kq];

#pragma unroll
            for (int i = 0; i < 4; ++i)
#pragma unroll
                for (int j = 0; j < 4; ++j)
                    acc[i][j] = __builtin_amdgcn_mfma_i32_16x16x64_i8(
                        af[i], bf[j], acc[i][j], 0, 0, 0);
        }

        __syncthreads();
    }

    // Epilogue. 16x16 C/D layout: col = lane&15, row = (lane>>4)*4 + reg
    const int col16 = lane & 15;
    const int rquad = (lane >> 4) * 4;
#pragma unroll
    for (int j = 0; j < 4; ++j) {
        const int col = bn * BN + wn * 64 + j * 16 + col16;
        float s = 0.05f * wscale[col];
        s = s / 0.1f;                      // match np ref arithmetic exactly
        const float bz = (float)bias[col];
#pragma unroll
        for (int i = 0; i < 4; ++i) {
            const int row0 = bm * BM + wm * 64 + i * 16 + rquad;
#pragma unroll
            for (int r = 0; r < 4; ++r) {
                float v = ((float)acc[i][j][r] + bz) * s;
                v = rintf(v);              // RTNE, matches np.round
                v = fminf(fmaxf(v, -128.0f), 127.0f);
                C[(size_t)(row0 + r) * N_DIM + col] = (int)v;
            }
        }
    }
}

extern "C" void kernel_launch(void* const* d_in, const int* in_sizes, int n_in,
                              void* d_out, int out_size, void* d_ws, size_t ws_size,
                              hipStream_t stream) {
    const int*   x32    = (const int*)d_in[0];     // int8 values promoted to int32
    const int*   w32    = (const int*)d_in[1];
    const int*   bias   = (const int*)d_in[2];
    const float* wscale = (const float*)d_in[3];
    int*         out    = (int*)d_out;

    int8_t* xp = (int8_t*)d_ws;                         // 32 MiB packed x
    int8_t* wp = xp + (size_t)M_DIM * K_DIM;            // 16 MiB packed w

    {
        long nx4   = (long)M_DIM * K_DIM / 4;
        long nw4   = (long)N_DIM * K_DIM / 4;
        long ntot4 = nx4 + nw4;
        pack_i8_fused_kernel<<<(int)((ntot4 + 255) / 256), 256, 0, stream>>>(
            (const int4*)x32, (const int4*)w32,
            (unsigned*)xp, (unsigned*)wp, nx4, ntot4);
    }

    dim3 grid(N_DIM / BN, M_DIM / BM);   // (32, 64)
    qgemm_i8_kernel<<<grid, 256, 0, stream>>>(xp, wp, bias, wscale, out);
}